// Round 1
// baseline (660.701 us; speedup 1.0000x reference)
//
#include <hip/hip_runtime.h>

#define FEPS 1e-12f

// Split-K GEMV: out[j] += sum_{i in chunk} f(v[i]) * W[i*C + j]  (+ bias when chunk 0)
// W row-major (R x C). Grid: (C/256, R/chunk). out must be pre-zeroed.
__global__ void gemv_atomic(const float* __restrict__ v,
                            const float* __restrict__ W,
                            const float* __restrict__ bias,
                            float* __restrict__ out,
                            int R, int C, int chunk, int relu_in) {
    int j = blockIdx.x * blockDim.x + threadIdx.x;
    if (j >= C) return;
    int i0 = blockIdx.y * chunk;
    int i1 = min(i0 + chunk, R);
    float acc = 0.0f;
    for (int i = i0; i < i1; ++i) {
        float vi = v[i];
        if (relu_in) vi = fmaxf(vi, 0.0f);
        acc += vi * W[(size_t)i * C + j];
    }
    if (blockIdx.y == 0) acc += bias[j];
    atomicAdd(&out[j], acc);
}

// weighted[m] = (q . keys[m]) / max(||keys[m]||, eps) * importance[m]
// (division by ||q|| deferred to topk kernel — positive scalar, order-preserving)
// One wave per row, 4 rows per 256-thread block.
__global__ void sims_kernel(const float* __restrict__ q,
                            const float* __restrict__ keys,
                            const float* __restrict__ imp,
                            float* __restrict__ weighted) {
    __shared__ float qs[1024];
    int t = threadIdx.x;
    #pragma unroll
    for (int p = 0; p < 4; ++p) qs[t + 256 * p] = q[t + 256 * p];
    __syncthreads();
    int wave = t >> 6, lane = t & 63;
    int m = blockIdx.x * 4 + wave;
    const float4* krow = (const float4*)(keys + (size_t)m * 1024);
    const float4* q4 = (const float4*)qs;
    float dot = 0.0f, sq = 0.0f;
    #pragma unroll
    for (int p = 0; p < 4; ++p) {
        float4 k4 = krow[lane + 64 * p];
        float4 qv = q4[lane + 64 * p];
        dot += k4.x * qv.x + k4.y * qv.y + k4.z * qv.z + k4.w * qv.w;
        sq  += k4.x * k4.x + k4.y * k4.y + k4.z * k4.z + k4.w * k4.w;
    }
    #pragma unroll
    for (int off = 32; off; off >>= 1) {
        dot += __shfl_down(dot, off);
        sq  += __shfl_down(sq, off);
    }
    if (lane == 0) {
        weighted[m] = dot * imp[m] / fmaxf(sqrtf(sq), FEPS);
    }
}

// Single block, 1024 threads: ||q||, top-3 of weighted[65536], softmax, gather
// 3 rows of values -> retrieved[1024]
__global__ void topk_retrieve(const float* __restrict__ q,
                              const float* __restrict__ weighted,
                              const float* __restrict__ values,
                              float* __restrict__ retrieved) {
    __shared__ float red[1024];
    __shared__ float mv[3 * 1024];
    __shared__ int   mi[3 * 1024];
    __shared__ float s_attn[3];
    __shared__ int   s_idx[3];
    __shared__ float s_qden;
    int t = threadIdx.x;

    // ||q||
    float qv = q[t];
    red[t] = qv * qv;
    __syncthreads();
    for (int s = 512; s > 0; s >>= 1) {
        if (t < s) red[t] += red[t + s];
        __syncthreads();
    }
    if (t == 0) s_qden = fmaxf(sqrtf(red[0]), FEPS);

    // per-thread top-3 over 64 strided elements (coalesced)
    float v0 = -INFINITY, v1 = -INFINITY, v2 = -INFINITY;
    int   i0 = -1, i1 = -1, i2 = -1;
    for (int k = 0; k < 64; ++k) {
        int idx = t + (k << 10);
        float val = weighted[idx];
        if (val > v0)      { v2 = v1; i2 = i1; v1 = v0; i1 = i0; v0 = val; i0 = idx; }
        else if (val > v1) { v2 = v1; i2 = i1; v1 = val; i1 = idx; }
        else if (val > v2) { v2 = val; i2 = idx; }
    }
    mv[t * 3 + 0] = v0; mv[t * 3 + 1] = v1; mv[t * 3 + 2] = v2;
    mi[t * 3 + 0] = i0; mi[t * 3 + 1] = i1; mi[t * 3 + 2] = i2;
    __syncthreads();

    // tree-merge top-3 lists
    for (int s = 512; s > 0; s >>= 1) {
        if (t < s) {
            float a0 = mv[t * 3], a1 = mv[t * 3 + 1], a2 = mv[t * 3 + 2];
            int   b0 = mi[t * 3], b1 = mi[t * 3 + 1], b2 = mi[t * 3 + 2];
            #pragma unroll
            for (int e = 0; e < 3; ++e) {
                float val = mv[(t + s) * 3 + e];
                int   idx = mi[(t + s) * 3 + e];
                if (val > a0)      { a2 = a1; b2 = b1; a1 = a0; b1 = b0; a0 = val; b0 = idx; }
                else if (val > a1) { a2 = a1; b2 = b1; a1 = val; b1 = idx; }
                else if (val > a2) { a2 = val; b2 = idx; }
            }
            mv[t * 3] = a0; mv[t * 3 + 1] = a1; mv[t * 3 + 2] = a2;
            mi[t * 3] = b0; mi[t * 3 + 1] = b1; mi[t * 3 + 2] = b2;
        }
        __syncthreads();
    }

    if (t == 0) {
        float qden = s_qden;
        float tv0 = mv[0] / qden, tv1 = mv[1] / qden, tv2 = mv[2] / qden;
        float mx = fmaxf(tv0, fmaxf(tv1, tv2));
        float e0 = expf(tv0 - mx), e1 = expf(tv1 - mx), e2 = expf(tv2 - mx);
        float sum = e0 + e1 + e2;
        s_attn[0] = e0 / sum; s_attn[1] = e1 / sum; s_attn[2] = e2 / sum;
        s_idx[0] = mi[0]; s_idx[1] = mi[1]; s_idx[2] = mi[2];
    }
    __syncthreads();

    float r = 0.0f;
    #pragma unroll
    for (int e = 0; e < 3; ++e)
        r += s_attn[e] * values[(size_t)s_idx[e] * 1024 + t];
    retrieved[t] = r;
}

extern "C" void kernel_launch(void* const* d_in, const int* in_sizes, int n_in,
                              void* d_out, int out_size, void* d_ws, size_t ws_size,
                              hipStream_t stream) {
    const float* x      = (const float*)d_in[0];
    const float* W1     = (const float*)d_in[1];
    const float* b1     = (const float*)d_in[2];
    const float* W2     = (const float*)d_in[3];
    const float* b2     = (const float*)d_in[4];
    const float* Wq     = (const float*)d_in[5];
    const float* bq     = (const float*)d_in[6];
    const float* Wout   = (const float*)d_in[7];
    const float* bout   = (const float*)d_in[8];
    const float* keys   = (const float*)d_in[9];
    const float* values = (const float*)d_in[10];
    const float* imp    = (const float*)d_in[11];
    float* out = (float*)d_out;
    float* ws  = (float*)d_ws;

    // ws layout (floats): [0,2048) h1 | [2048,5120) combined(last_hidden|retrieved)
    //                     [5120,6144) q | [6144,71680) weighted
    float* h1       = ws;
    float* combined = ws + 2048;
    float* q        = ws + 5120;
    float* weighted = ws + 6144;

    // only the last sequence position contributes to the output
    const float* xlast = x + (size_t)(4096 - 1) * 2048;

    hipMemsetAsync(d_ws, 0, 6144 * sizeof(float), stream);   // atomic accumulators
    hipMemsetAsync(d_out, 0, (size_t)out_size * sizeof(float), stream);

    // h1 = xlast @ W1 + b1                       (2048x2048, 16 MB)
    gemv_atomic<<<dim3(8, 32), 256, 0, stream>>>(xlast, W1, b1, h1, 2048, 2048, 64, 0);
    // last_hidden = relu(h1) @ W2 + b2 -> combined[0:2048]
    gemv_atomic<<<dim3(8, 32), 256, 0, stream>>>(h1, W2, b2, combined, 2048, 2048, 64, 1);
    // q = last_hidden @ Wq + bq
    gemv_atomic<<<dim3(4, 32), 256, 0, stream>>>(combined, Wq, bq, q, 2048, 1024, 64, 0);
    // weighted[m] over 65536 key rows           (256 MB — dominant)
    sims_kernel<<<16384, 256, 0, stream>>>(q, keys, imp, weighted);
    // top-3 + softmax + values gather -> combined[2048:3072]
    topk_retrieve<<<1, 1024, 0, stream>>>(q, weighted, values, combined + 2048);
    // out = combined @ Wout + bout              (3072x2048, 24 MB)
    gemv_atomic<<<dim3(8, 32), 256, 0, stream>>>(combined, Wout, bout, out, 3072, 2048, 96, 0);
}

// Round 2
// 610.084 us; speedup vs baseline: 1.0830x; 1.0830x over previous
//
#include <hip/hip_runtime.h>

#define FEPS 1e-12f

// Split-K GEMV, float4 columns: out[j..j+3] += sum_{i in chunk} f(v[i]) * W[i,j..j+3]
// W row-major (R x C). grid = (C/1024, R/chunk), block = 256. out pre-zeroed.
template<int RELU>
__global__ void gemv_atomic4(const float* __restrict__ v,
                             const float* __restrict__ W,
                             const float* __restrict__ bias,
                             float* __restrict__ out,
                             int C, int chunk) {
    int j = (blockIdx.x * 256 + threadIdx.x) * 4;
    int i0 = blockIdx.y * chunk;
    float4 acc = make_float4(0.f, 0.f, 0.f, 0.f);
    for (int i = i0; i < i0 + chunk; ++i) {
        float vi = v[i];
        if (RELU) vi = fmaxf(vi, 0.f);
        float4 w = *(const float4*)(W + (size_t)i * C + j);
        acc.x += vi * w.x; acc.y += vi * w.y;
        acc.z += vi * w.z; acc.w += vi * w.w;
    }
    if (blockIdx.y == 0) {
        float4 b = *(const float4*)(bias + j);
        acc.x += b.x; acc.y += b.y; acc.z += b.z; acc.w += b.w;
    }
    atomicAdd(&out[j + 0], acc.x);
    atomicAdd(&out[j + 1], acc.y);
    atomicAdd(&out[j + 2], acc.z);
    atomicAdd(&out[j + 3], acc.w);
}

// Each block: 64 key rows (wave w -> rows base+w*16 .. +15). Computes
// weighted[m] = (q.k_m) * imp[m] / max(||k_m||,eps)  (÷||q|| deferred — positive
// scalar, order-preserving) and emits the block's top-3 (val, idx).
__global__ void sims_top3(const float* __restrict__ q,
                          const float* __restrict__ keys,
                          const float* __restrict__ imp,
                          float* __restrict__ cand_val,
                          int* __restrict__ cand_idx) {
    __shared__ float qs[1024];
    __shared__ float wv[4 * 3];
    __shared__ int   wi[4 * 3];
    int t = threadIdx.x;
    #pragma unroll
    for (int p = 0; p < 4; ++p) qs[t + 256 * p] = q[t + 256 * p];
    __syncthreads();
    int wave = t >> 6, lane = t & 63;
    const float4* q4 = (const float4*)qs;
    float4 qv[4];
    #pragma unroll
    for (int p = 0; p < 4; ++p) qv[p] = q4[lane + 64 * p];

    float v0 = -INFINITY, v1 = -INFINITY, v2 = -INFINITY;
    int   i0 = -1, i1 = -1, i2 = -1;
    int mbase = blockIdx.x * 64 + wave * 16;
    for (int r = 0; r < 16; ++r) {
        int m = mbase + r;
        const float4* krow = (const float4*)(keys + (size_t)m * 1024);
        float dot = 0.f, sq = 0.f;
        #pragma unroll
        for (int p = 0; p < 4; ++p) {
            float4 k = krow[lane + 64 * p];
            dot += k.x * qv[p].x + k.y * qv[p].y + k.z * qv[p].z + k.w * qv[p].w;
            sq  += k.x * k.x + k.y * k.y + k.z * k.z + k.w * k.w;
        }
        #pragma unroll
        for (int off = 32; off; off >>= 1) {
            dot += __shfl_down(dot, off);
            sq  += __shfl_down(sq, off);
        }
        if (lane == 0) {
            float val = dot * imp[m] / fmaxf(sqrtf(sq), FEPS);
            if (val > v0)      { v2 = v1; i2 = i1; v1 = v0; i1 = i0; v0 = val; i0 = m; }
            else if (val > v1) { v2 = v1; i2 = i1; v1 = val; i1 = m; }
            else if (val > v2) { v2 = val; i2 = m; }
        }
    }
    if (lane == 0) {
        wv[wave * 3 + 0] = v0; wv[wave * 3 + 1] = v1; wv[wave * 3 + 2] = v2;
        wi[wave * 3 + 0] = i0; wi[wave * 3 + 1] = i1; wi[wave * 3 + 2] = i2;
    }
    __syncthreads();
    if (t == 0) {
        float a0 = -INFINITY, a1 = -INFINITY, a2 = -INFINITY;
        int   b0 = -1, b1 = -1, b2 = -1;
        for (int e = 0; e < 12; ++e) {
            float val = wv[e]; int idx = wi[e];
            if (val > a0)      { a2 = a1; b2 = b1; a1 = a0; b1 = b0; a0 = val; b0 = idx; }
            else if (val > a1) { a2 = a1; b2 = b1; a1 = val; b1 = idx; }
            else if (val > a2) { a2 = val; b2 = idx; }
        }
        cand_val[blockIdx.x * 3 + 0] = a0; cand_idx[blockIdx.x * 3 + 0] = b0;
        cand_val[blockIdx.x * 3 + 1] = a1; cand_idx[blockIdx.x * 3 + 1] = b1;
        cand_val[blockIdx.x * 3 + 2] = a2; cand_idx[blockIdx.x * 3 + 2] = b2;
    }
}

// One block, 1024 threads: ||q||, top-3 of 3072 candidates, softmax,
// gather 3 rows of values -> retrieved[1024].
__global__ void finalize_retrieve(const float* __restrict__ q,
                                  const float* __restrict__ cand_val,
                                  const int* __restrict__ cand_idx,
                                  const float* __restrict__ values,
                                  float* __restrict__ retrieved) {
    __shared__ float red[1024];
    __shared__ float mv[3 * 1024];
    __shared__ int   mi[3 * 1024];
    __shared__ float s_attn[3];
    __shared__ int   s_idx[3];
    __shared__ float s_qden;
    int t = threadIdx.x;

    float qv = q[t];
    red[t] = qv * qv;
    __syncthreads();
    for (int s = 512; s > 0; s >>= 1) {
        if (t < s) red[t] += red[t + s];
        __syncthreads();
    }
    if (t == 0) s_qden = fmaxf(sqrtf(red[0]), FEPS);

    // per-thread top-3 over candidates t, t+1024, t+2048
    float v0 = -INFINITY, v1 = -INFINITY, v2 = -INFINITY;
    int   i0 = -1, i1 = -1, i2 = -1;
    #pragma unroll
    for (int k = 0; k < 3; ++k) {
        int c = t + (k << 10);
        float val = cand_val[c];
        int   idx = cand_idx[c];
        if (val > v0)      { v2 = v1; i2 = i1; v1 = v0; i1 = i0; v0 = val; i0 = idx; }
        else if (val > v1) { v2 = v1; i2 = i1; v1 = val; i1 = idx; }
        else if (val > v2) { v2 = val; i2 = idx; }
    }
    mv[t * 3 + 0] = v0; mv[t * 3 + 1] = v1; mv[t * 3 + 2] = v2;
    mi[t * 3 + 0] = i0; mi[t * 3 + 1] = i1; mi[t * 3 + 2] = i2;
    __syncthreads();

    for (int s = 512; s > 0; s >>= 1) {
        if (t < s) {
            float a0 = mv[t * 3], a1 = mv[t * 3 + 1], a2 = mv[t * 3 + 2];
            int   b0 = mi[t * 3], b1 = mi[t * 3 + 1], b2 = mi[t * 3 + 2];
            #pragma unroll
            for (int e = 0; e < 3; ++e) {
                float val = mv[(t + s) * 3 + e];
                int   idx = mi[(t + s) * 3 + e];
                if (val > a0)      { a2 = a1; b2 = b1; a1 = a0; b1 = b0; a0 = val; b0 = idx; }
                else if (val > a1) { a2 = a1; b2 = b1; a1 = val; b1 = idx; }
                else if (val > a2) { a2 = val; b2 = idx; }
            }
            mv[t * 3] = a0; mv[t * 3 + 1] = a1; mv[t * 3 + 2] = a2;
            mi[t * 3] = b0; mi[t * 3 + 1] = b1; mi[t * 3 + 2] = b2;
        }
        __syncthreads();
    }

    if (t == 0) {
        float qden = s_qden;
        float tv0 = mv[0] / qden, tv1 = mv[1] / qden, tv2 = mv[2] / qden;
        float mx = fmaxf(tv0, fmaxf(tv1, tv2));
        float e0 = expf(tv0 - mx), e1 = expf(tv1 - mx), e2 = expf(tv2 - mx);
        float sum = e0 + e1 + e2;
        s_attn[0] = e0 / sum; s_attn[1] = e1 / sum; s_attn[2] = e2 / sum;
        s_idx[0] = mi[0]; s_idx[1] = mi[1]; s_idx[2] = mi[2];
    }
    __syncthreads();

    float r = 0.0f;
    #pragma unroll
    for (int e = 0; e < 3; ++e)
        r += s_attn[e] * values[(size_t)s_idx[e] * 1024 + t];
    retrieved[t] = r;
}

extern "C" void kernel_launch(void* const* d_in, const int* in_sizes, int n_in,
                              void* d_out, int out_size, void* d_ws, size_t ws_size,
                              hipStream_t stream) {
    const float* x      = (const float*)d_in[0];
    const float* W1     = (const float*)d_in[1];
    const float* b1     = (const float*)d_in[2];
    const float* W2     = (const float*)d_in[3];
    const float* b2     = (const float*)d_in[4];
    const float* Wq     = (const float*)d_in[5];
    const float* bq     = (const float*)d_in[6];
    const float* Wout   = (const float*)d_in[7];
    const float* bout   = (const float*)d_in[8];
    const float* keys   = (const float*)d_in[9];
    const float* values = (const float*)d_in[10];
    const float* imp    = (const float*)d_in[11];
    float* out = (float*)d_out;
    float* ws  = (float*)d_ws;

    // ws layout (floats):
    // [0,2048)      h1
    // [2048,5120)   comb = last_hidden (2048) | retrieved (1024)
    // [5120,6144)   q
    // [6144,9216)   cand_val (3072)
    // [9216,12288)  cand_idx (3072 ints)
    float* h1       = ws;
    float* comb     = ws + 2048;
    float* retr     = ws + 4096;
    float* q        = ws + 5120;
    float* cand_val = ws + 6144;
    int*   cand_idx = (int*)(ws + 9216);

    const float* xlast = x + (size_t)(4096 - 1) * 2048;  // only last position matters

    hipMemsetAsync(d_ws, 0, 6144 * sizeof(float), stream);   // atomic accumulators
    hipMemsetAsync(d_out, 0, (size_t)out_size * sizeof(float), stream);

    // h1 = xlast @ W1 + b1                       (16 MB)
    gemv_atomic4<0><<<dim3(2, 128), 256, 0, stream>>>(xlast, W1, b1, h1, 2048, 16);
    // last_hidden = relu(h1) @ W2 + b2           (16 MB)
    gemv_atomic4<1><<<dim3(2, 128), 256, 0, stream>>>(h1, W2, b2, comb, 2048, 16);
    // q = last_hidden @ Wq + bq                  (8 MB)
    gemv_atomic4<0><<<dim3(1, 128), 256, 0, stream>>>(comb, Wq, bq, q, 1024, 16);
    // sims + per-block top-3 over 65536 key rows (256 MB — dominant)
    sims_top3<<<1024, 256, 0, stream>>>(q, keys, imp, cand_val, cand_idx);
    // global top-3 + softmax + values gather -> retrieved
    finalize_retrieve<<<1, 1024, 0, stream>>>(q, cand_val, cand_idx, values, retr);
    // out = comb @ Wout + bout                   (24 MB)
    gemv_atomic4<0><<<dim3(2, 128), 256, 0, stream>>>(comb, Wout, bout, out, 2048, 24);
}